// Round 10
// baseline (140.124 us; speedup 1.0000x reference)
//
#include <hip/hip_runtime.h>
#include <hip/hip_bf16.h>

// CrossAttentionSequencePool — fp16 MFMA; r7 base + reg-A final GEMM.
//  convert/chunkmax/segscan/segpref/scanwrite/qmlp/gemm_a: r7-verbatim (best 125.8)
//  K5 (new): out = yq @ h1^T /16 + c[m], BM=256 BN=128, 8 waves:
//   - A (yq, 512KB, L2-resident on every XCD) read DIRECTLY from global into
//     fragments (global_load_dwordx4, no LDS round trip, no swizzle needed)
//   - B (h1) only operand staged: 8KB/panel, 1 gload_lds/thread, 16KB LDS
//   - counted-vmcnt ledger per iter: FIFO {stage(tt+1):1, fa:4, stage(tt+2):1}
//     -> vmcnt(1) retires fa + publishes tile tt+1 in one wait
//  r6/r9 lesson: 2-barrier depth-2 schedule is the local optimum — this round
//  changes operand structure, not the schedule.

#define NK 32768
#define DIM 256
#define MQ 1024
#define CHUNK 32
#define NCHUNK (NK / CHUNK) // 1024
#define NSEG 32
#define SEGCH (NCHUNK / NSEG) // 32

typedef _Float16 f16;
typedef _Float16 f16x2 __attribute__((ext_vector_type(2)));
typedef _Float16 f16x8 __attribute__((ext_vector_type(8)));
typedef float f32x4 __attribute__((ext_vector_type(4)));

__device__ __forceinline__ void gload16(const void* g, void* l) {
    __builtin_amdgcn_global_load_lds(
        (const __attribute__((address_space(1))) unsigned int*)g,
        (__attribute__((address_space(3))) unsigned int*)l, 16, 0, 0);
}

// ---------------- scan ----------------
__global__ __launch_bounds__(128) void chunkmax_kernel(const float* __restrict__ key,
                                                       f16* __restrict__ keyf,
                                                       float* __restrict__ cmax) {
    int t = threadIdx.x, c = blockIdx.x;
    int c0 = t * 2;
    float m0 = -INFINITY, m1 = -INFINITY;
#pragma unroll 8
    for (int r = 0; r < CHUNK; ++r) {
        int gr = c * CHUNK + r;
        float2 kv = *reinterpret_cast<const float2*>(key + (size_t)gr * DIM + c0);
        *reinterpret_cast<f16x2*>(keyf + (size_t)gr * DIM + c0) = (f16x2){(f16)kv.x, (f16)kv.y};
        m0 = fmaxf(m0, kv.x);
        m1 = fmaxf(m1, kv.y);
    }
    *reinterpret_cast<float2*>(cmax + c * DIM + c0) = make_float2(m0, m1);
}

__global__ __launch_bounds__(256) void segscan_kernel(const float* __restrict__ cmax,
                                                      float* __restrict__ pbef,
                                                      float* __restrict__ paft,
                                                      float* __restrict__ stot) {
    int col = threadIdx.x, b = blockIdx.x;
    int dir = b >> 5, s = b & 31;
    float run = -INFINITY;
    if (dir == 0) {
#pragma unroll 8
        for (int i = 0; i < SEGCH; ++i) {
            int c = s * SEGCH + i;
            pbef[c * DIM + col] = run;
            run = fmaxf(run, cmax[c * DIM + col]);
        }
        stot[s * DIM + col] = run;
    } else {
#pragma unroll 8
        for (int i = SEGCH - 1; i >= 0; --i) {
            int c = s * SEGCH + i;
            paft[c * DIM + col] = run;
            run = fmaxf(run, cmax[c * DIM + col]);
        }
        stot[(NSEG + s) * DIM + col] = run;
    }
}

__global__ __launch_bounds__(256) void segpref_kernel(const float* __restrict__ stot,
                                                      float* __restrict__ spref) {
    int col = threadIdx.x;
    float run = -INFINITY;
#pragma unroll
    for (int s = 0; s < NSEG; ++s) {
        spref[s * DIM + col] = run;
        run = fmaxf(run, stot[s * DIM + col]);
    }
    run = -INFINITY;
#pragma unroll
    for (int s = NSEG - 1; s >= 0; --s) {
        spref[(NSEG + s) * DIM + col] = run;
        run = fmaxf(run, stot[(NSEG + s) * DIM + col]);
    }
}

__global__ __launch_bounds__(128) void scanwrite_kernel(const f16* __restrict__ keyf,
                                                        const float* __restrict__ pbef,
                                                        const float* __restrict__ paft,
                                                        const float* __restrict__ spref,
                                                        f16* __restrict__ ba) {
    __shared__ f16 sk[CHUNK * DIM];
    int t = threadIdx.x, c = blockIdx.x, s = c >> 5;
    int c0 = t * 2;
    float r0 = fmaxf(pbef[c * DIM + c0], spref[s * DIM + c0]);
    float r1 = fmaxf(pbef[c * DIM + c0 + 1], spref[s * DIM + c0 + 1]);
    for (int r = 0; r < CHUNK; ++r) {
        int gr = c * CHUNK + r;
        f16x2 kv = *reinterpret_cast<const f16x2*>(keyf + (size_t)gr * DIM + c0);
        *reinterpret_cast<f16x2*>(sk + r * DIM + c0) = kv;
        *reinterpret_cast<f16x2*>(ba + (size_t)gr * 512 + c0) =
            (f16x2){(f16)(gr == 0 ? 0.f : r0), (f16)(gr == 0 ? 0.f : r1)};
        r0 = fmaxf(r0, (float)kv.x);
        r1 = fmaxf(r1, (float)kv.y);
    }
    r0 = fmaxf(paft[c * DIM + c0], spref[(NSEG + s) * DIM + c0]);
    r1 = fmaxf(paft[c * DIM + c0 + 1], spref[(NSEG + s) * DIM + c0 + 1]);
    for (int r = CHUNK - 1; r >= 0; --r) {
        int gr = c * CHUNK + r;
        f16x2 kv = *reinterpret_cast<const f16x2*>(sk + r * DIM + c0);
        *reinterpret_cast<f16x2*>(ba + (size_t)gr * 512 + 256 + c0) =
            (f16x2){(f16)(gr == NK - 1 ? 0.f : r0), (f16)(gr == NK - 1 ? 0.f : r1)};
        r0 = fmaxf(r0, (float)kv.x);
        r1 = fmaxf(r1, (float)kv.y);
    }
}

// ---------------- convert ----------------
__global__ __launch_bounds__(256) void convert_kernel(
    const float* __restrict__ q, const float* __restrict__ q1w, const float* __restrict__ q2w,
    const float* __restrict__ k1w, const float* __restrict__ k2w,
    f16* qf, f16* q1f, f16* q2f, f16* k1f, f16* k2t) {
    int i = blockIdx.x * 256 + threadIdx.x;
    if (i < 262144)      { qf[i] = (f16)q[i]; }
    else if (i < 327680) { int o = i - 262144; q1f[o] = (f16)q1w[o]; }
    else if (i < 393216) { int o = i - 327680; q2f[o] = (f16)q2w[o]; }
    else if (i < 589824) { int o = i - 393216; k1f[o] = (f16)k1w[o]; }
    else { // k2t[n][k] = k2[k][n]
        int o = i - 589824;
        int k = o >> 8, n = o & 255;
        k2t[n * 256 + k] = (f16)k2w[o];
    }
}

// ---------------- fused query MLP (r7-verbatim) ----------------
__global__ __launch_bounds__(256) void qmlp_kernel(
    const f16* __restrict__ qf, const f16* __restrict__ q1f,
    const f16* __restrict__ q2f, const f16* __restrict__ k2t,
    const float* __restrict__ q1_b, const float* __restrict__ q2_b,
    const float* __restrict__ k2_b,
    f16* __restrict__ yq, float* __restrict__ cvec) {
    __shared__ __align__(16) f16 hbuf[8 * 64 * 32];
    __shared__ __align__(16) f16 sB[2][256 * 32];
    __shared__ float cpart[64][4];
    const int t = threadIdx.x, lane = t & 63, wid = t >> 6;
    const int m0 = blockIdx.x * 64;
    const int l15 = lane & 15, l4 = lane >> 4, r16 = lane >> 2;
    const int cSw = ((lane & 3) ^ ((lane >> 3) & 3)) * 8;
    const int sw = (l4 ^ ((l15 >> 1) & 3)) * 8;

    auto hb_addr = [&](int row, int col) {
        return (col >> 5) * 2048 + row * 32 +
               ((((col & 31) >> 3) ^ ((row >> 1) & 3)) << 3) + (col & 7);
    };
    auto stageB = [&](int u, int b) {
        const f16* B = u < 8 ? q1f : (u < 16 ? q2f : k2t);
        const int tt = u & 7;
#pragma unroll
        for (int cc = 0; cc < 4; ++cc) {
            int row = wid * 64 + cc * 16 + r16;
            gload16(B + (size_t)row * 256 + tt * 32 + cSw,
                    (char*)&sB[b][0] + (wid * 4 + cc) * 1024);
        }
    };

    f32x4 acc[4][4];
#define ZACC                                                        \
    _Pragma("unroll") for (int i = 0; i < 4; ++i)                   \
        _Pragma("unroll") for (int j = 0; j < 4; ++j) {             \
            acc[i][j][0] = 0.f; acc[i][j][1] = 0.f;                 \
            acc[i][j][2] = 0.f; acc[i][j][3] = 0.f;                 \
        }

#pragma unroll
    for (int tt = 0; tt < 8; ++tt)
        gload16(qf + (size_t)(m0 + wid * 16 + r16) * 256 + tt * 32 + cSw,
                (char*)hbuf + tt * 4096 + wid * 1024);
    stageB(0, 0);
    stageB(1, 1);
    asm volatile("s_waitcnt vmcnt(4)" ::: "memory");
    __builtin_amdgcn_s_barrier();

    ZACC
    for (int u = 0; u < 24; ++u) {
        const int tt = u & 7, b = u & 1;
        f16x8 fa[4], fb[4];
#pragma unroll
        for (int i = 0; i < 4; ++i)
            fa[i] = *reinterpret_cast<const f16x8*>(&hbuf[tt * 2048 + (i * 16 + l15) * 32 + sw]);
#pragma unroll
        for (int j = 0; j < 4; ++j)
            fb[j] = *reinterpret_cast<const f16x8*>(&sB[b][(wid * 64 + j * 16 + l15) * 32 + sw]);
        asm volatile("s_waitcnt lgkmcnt(0)" ::: "memory");
        __builtin_amdgcn_s_barrier();
        if (u + 2 < 24) stageB(u + 2, b);
        __builtin_amdgcn_s_setprio(1);
#pragma unroll
        for (int i = 0; i < 4; ++i)
#pragma unroll
            for (int j = 0; j < 4; ++j)
                acc[i][j] = __builtin_amdgcn_mfma_f32_16x16x32_f16(fa[i], fb[j], acc[i][j], 0, 0, 0);
        __builtin_amdgcn_s_setprio(0);
        if (u == 7) {
#pragma unroll
            for (int j = 0; j < 4; ++j) {
                int col = wid * 64 + j * 16 + l15;
                float bv = q1_b[col];
#pragma unroll
                for (int i = 0; i < 4; ++i)
#pragma unroll
                    for (int r = 0; r < 4; ++r)
                        hbuf[hb_addr(i * 16 + l4 * 4 + r, col)] =
                            (f16)fmaxf(acc[i][j][r] + bv, 0.f);
            }
            asm volatile("s_waitcnt lgkmcnt(0)" ::: "memory");
            ZACC
        }
        if (u == 15) {
#pragma unroll
            for (int j = 0; j < 4; ++j) {
                int col = wid * 64 + j * 16 + l15;
                float bv = q2_b[col];
#pragma unroll
                for (int i = 0; i < 4; ++i)
#pragma unroll
                    for (int r = 0; r < 4; ++r)
                        hbuf[hb_addr(i * 16 + l4 * 4 + r, col)] = (f16)(acc[i][j][r] + bv);
            }
            asm volatile("s_waitcnt lgkmcnt(0)" ::: "memory");
            ZACC
        }
        if (u + 2 < 24) {
            asm volatile("s_waitcnt vmcnt(4)" ::: "memory");
        } else {
            asm volatile("s_waitcnt vmcnt(0)" ::: "memory");
        }
        __builtin_amdgcn_s_barrier();
    }
#undef ZACC

#pragma unroll
    for (int j = 0; j < 4; ++j) {
        int col = wid * 64 + j * 16 + l15;
#pragma unroll
        for (int i = 0; i < 4; ++i)
#pragma unroll
            for (int r = 0; r < 4; ++r)
                yq[(size_t)(m0 + i * 16 + l4 * 4 + r) * 256 + col] = (f16)acc[i][j][r];
    }
    {
        int row = t & 63, qtr = t >> 6;
        float s = 0.f;
        for (int k = qtr * 64; k < qtr * 64 + 64; ++k)
            s += (float)hbuf[hb_addr(row, k)] * k2_b[k];
        cpart[row][qtr] = s;
    }
    __syncthreads();
    if (t < 64)
        cvec[m0 + t] = (cpart[t][0] + cpart[t][1] + cpart[t][2] + cpart[t][3]) * 0.0625f;
}

// ---------------- K4: fp16 MFMA GEMM (NT), depth-2 pipeline (r7-verbatim) ----------------
template <int K, int SWZ, bool TWOPART, bool RELU, bool OUTF16>
__global__ __launch_bounds__(256, 4) void gemm_f16(
    const f16* __restrict__ A0, const f16* __restrict__ A1,
    const f16* __restrict__ B,
    const float* __restrict__ bias, const float* __restrict__ rowbias,
    float* __restrict__ Cf, f16* __restrict__ Ch,
    int N, float scale) {
    __shared__ __align__(16) f16 sA[2][128 * 32];
    __shared__ __align__(16) f16 sB[2][128 * 32];
    const int t = threadIdx.x;
    const int lane = t & 63, wid = t >> 6;

    int mt, nt;
    if (SWZ == 1) {
        int bid = blockIdx.y * gridDim.x + blockIdx.x;
        int xcd = bid & 7, i = bid >> 3;
        mt = xcd * 32 + (i >> 1);
        nt = i & 1;
    } else {
        mt = blockIdx.y;
        nt = blockIdx.x;
    }
    const int m0 = mt * 128, n0 = nt * 128;
    const int wr = wid >> 1, wc = wid & 1;
    const int l15 = lane & 15, l4 = lane >> 4;
    constexpr int T = K / 32;

    const int row0 = wid * 16 + (lane >> 2);
    const int row1 = row0 + 64;
    const int cSw = ((lane & 3) ^ ((lane >> 3) & 3)) * 8;
    const unsigned off0 = (unsigned)(wid * 1024);
    const unsigned off1 = off0 + 4096;

    f32x4 acc[4][4];
#pragma unroll
    for (int i = 0; i < 4; ++i)
#pragma unroll
        for (int j = 0; j < 4; ++j) {
            acc[i][j][0] = 0.f; acc[i][j][1] = 0.f; acc[i][j][2] = 0.f; acc[i][j][3] = 0.f;
        }

    auto aadr = [&](int row, int tt) -> const f16* {
        if (TWOPART && tt >= 8) return A1 + (size_t)row * 512 + (tt - 8) * 32 + cSw;
        return A0 + (size_t)row * (TWOPART ? 256 : K) + tt * 32 + cSw;
    };
    auto stage = [&](int tt, int bb) {
        gload16(aadr(m0 + row0, tt), (char*)&sA[bb][0] + off0);
        gload16(aadr(m0 + row1, tt), (char*)&sA[bb][0] + off1);
        gload16(B + (size_t)(n0 + row0) * K + tt * 32 + cSw, (char*)&sB[bb][0] + off0);
        gload16(B + (size_t)(n0 + row1) * K + tt * 32 + cSw, (char*)&sB[bb][0] + off1);
    };

    stage(0, 0);
    stage(1, 1);
    asm volatile("s_waitcnt vmcnt(4)" ::: "memory");
    __builtin_amdgcn_s_barrier();

    for (int tt = 0; tt < T; ++tt) {
        const int b = tt & 1;
        f16x8 fa[4], fb[4];
#pragma unroll
        for (int i = 0; i < 4; ++i) {
            const int sw = (l4 ^ ((l15 >> 1) & 3)) * 8;
            fa[i] = *reinterpret_cast<const f16x8*>(&sA[b][(wr * 64 + i * 16 + l15) * 32 + sw]);
            fb[i] = *reinterpret_cast<const f16x8*>(&sB[b][(wc * 64 + i * 16 + l15) * 32 + sw]);
        }
        asm volatile("s_waitcnt lgkmcnt(0)" ::: "memory");
        __builtin_amdgcn_s_barrier();
        if (tt + 2 < T) stage(tt + 2, b);
        __builtin_amdgcn_s_setprio(1);
#pragma unroll
        for (int i = 0; i < 4; ++i)
#pragma unroll
            for (int j = 0; j < 4; ++j)
                acc[i][j] = __builtin_amdgcn_mfma_f32_16x16x32_f16(fa[i], fb[j], acc[i][j], 0, 0, 0);
        __builtin_amdgcn_s_setprio(0);
        if (tt + 2 < T) {
            asm volatile("s_waitcnt vmcnt(4)" ::: "memory");
        } else {
            asm volatile("s_waitcnt vmcnt(0)" ::: "memory");
        }
        __builtin_amdgcn_s_barrier();
    }

#pragma unroll
    for (int j = 0; j < 4; ++j) {
        int col = n0 + wc * 64 + j * 16 + l15;
        float bv = bias ? bias[col] : 0.0f;
#pragma unroll
        for (int i = 0; i < 4; ++i) {
            int rbase = m0 + wr * 64 + i * 16 + l4 * 4;
#pragma unroll
            for (int r = 0; r < 4; ++r) {
                float v = acc[i][j][r] + bv;
                if (RELU) v = fmaxf(v, 0.0f);
                v *= scale;
                if (rowbias) v += rowbias[rbase + r];
                size_t idx = (size_t)(rbase + r) * N + col;
                if (OUTF16) Ch[idx] = (f16)v;
                else Cf[idx] = v;
            }
        }
    }
}

// ---------------- K5: final GEMM, reg-A (yq from L2), BM=256 BN=128 ----------------
// out[m][n] = (sum_k yq[m][k] h1[n][k]) / 16 + cvec[m]
// 8 waves (512 thr), wave grid 4x2 (m x n), each wave 64x64 = acc[4][4].
// A frags loaded straight from global (yq L2-resident); only B (h1) staged.
// vmcnt FIFO per iter: {stage(tt+1):1, fa:4, stage(tt+2):1} -> vmcnt(1).
__global__ __launch_bounds__(512, 4) void gemm_final(
    const f16* __restrict__ yq, const f16* __restrict__ h1,
    const float* __restrict__ cvec, float* __restrict__ out) {
    __shared__ __align__(16) f16 sB[2][128 * 32]; // 16KB total
    const int t = threadIdx.x, lane = t & 63, wid = t >> 6;
    // XCD swizzle: grid 1024 = 256 n-tiles x 4 m-tiles (1024 % 8 == 0, bijective)
    int bid = blockIdx.y * gridDim.x + blockIdx.x;
    int xcd = bid & 7, ii = bid >> 3;
    const int nt = xcd * 32 + (ii & 31);
    const int mt = ii >> 5;
    const int m0 = mt * 256, n0 = nt * 128;
    const int wr = wid >> 1, wc = wid & 1; // wr 0..3 (m), wc 0..1 (n)
    const int l15 = lane & 15, l4 = lane >> 4;

    // B staging: 128x32 panel = 8 chunks of 1KB; wave wid stages chunk wid (1 gload).
    const int brow = wid * 16 + (lane >> 2);
    const int cSw = ((lane & 3) ^ ((lane >> 3) & 3)) * 8;
    const unsigned boff = (unsigned)(wid * 1024);

    f32x4 acc[4][4];
#pragma unroll
    for (int i = 0; i < 4; ++i)
#pragma unroll
        for (int j = 0; j < 4; ++j) {
            acc[i][j][0] = 0.f; acc[i][j][1] = 0.f; acc[i][j][2] = 0.f; acc[i][j][3] = 0.f;
        }

    auto stage = [&](int tt, int bb) { // 1 load/thread
        gload16(h1 + (size_t)(n0 + brow) * 256 + tt * 32 + cSw, (char*)&sB[bb][0] + boff);
    };

    stage(0, 0);
    stage(1, 1);
    asm volatile("s_waitcnt vmcnt(1)" ::: "memory"); // tile 0 landed, tile 1 in flight
    __builtin_amdgcn_s_barrier();

    for (int tt = 0; tt < 8; ++tt) {
        const int b = tt & 1;
        f16x8 fa[4], fb[4];
        // A frags direct from global — issued first (oldest in vmcnt FIFO after stage(tt+1))
#pragma unroll
        for (int i = 0; i < 4; ++i)
            fa[i] = *reinterpret_cast<const f16x8*>(
                yq + (size_t)(m0 + wr * 64 + i * 16 + l15) * 256 + tt * 32 + l4 * 8);
#pragma unroll
        for (int j = 0; j < 4; ++j) {
            const int sw = (l4 ^ ((l15 >> 1) & 3)) * 8;
            fb[j] = *reinterpret_cast<const f16x8*>(&sB[b][(wc * 64 + j * 16 + l15) * 32 + sw]);
        }
        asm volatile("s_waitcnt lgkmcnt(0)" ::: "memory"); // fb in regs
        __builtin_amdgcn_s_barrier();                      // all waves done with sB[b]
        if (tt + 2 < 8) stage(tt + 2, b);                  // overwrite sB[b]
        // retire fa + stage(tt+1); leave stage(tt+2) in flight
        if (tt + 2 < 8) {
            asm volatile("s_waitcnt vmcnt(1)" ::: "memory");
        } else {
            asm volatile("s_waitcnt vmcnt(0)" ::: "memory");
        }
        __builtin_amdgcn_s_setprio(1);
#pragma unroll
        for (int i = 0; i < 4; ++i)
#pragma unroll
            for (int j = 0; j < 4; ++j)
                acc[i][j] = __builtin_amdgcn_mfma_f32_16x16x32_f16(fa[i], fb[j], acc[i][j], 0, 0, 0);
        __builtin_amdgcn_s_setprio(0);
        __builtin_amdgcn_s_barrier(); // publishes tile tt+1 ready / sB[b] restaged
    }

    // epilogue: C row = 4*(lane>>4)+reg, col = lane&15; nontemporal fp32 stream
#pragma unroll
    for (int j = 0; j < 4; ++j) {
        int col = n0 + wc * 64 + j * 16 + l15;
#pragma unroll
        for (int i = 0; i < 4; ++i) {
            int rbase = m0 + wr * 64 + i * 16 + l4 * 4;
#pragma unroll
            for (int r = 0; r < 4; ++r) {
                float v = acc[i][j][r] * 0.0625f + cvec[rbase + r];
                __builtin_nontemporal_store(v, out + (size_t)(rbase + r) * NK + col);
            }
        }
    }
}

extern "C" void kernel_launch(void* const* d_in, const int* in_sizes, int n_in,
                              void* d_out, int out_size, void* d_ws, size_t ws_size,
                              hipStream_t stream) {
    const float* query = (const float*)d_in[0];
    const float* key   = (const float*)d_in[1];
    const float* q1_w  = (const float*)d_in[2];
    const float* q1_b  = (const float*)d_in[3];
    const float* q2_w  = (const float*)d_in[4];
    const float* q2_b  = (const float*)d_in[5];
    const float* k1_w  = (const float*)d_in[6];
    const float* k1_b  = (const float*)d_in[7];
    const float* k2_w  = (const float*)d_in[8];
    const float* k2_b  = (const float*)d_in[9];
    float* out = (float*)d_out;

    char* ws = (char*)d_ws;
    size_t o = 0;
    f16* keyf = (f16*)(ws + o); o += (size_t)NK * DIM * 2;   // 16 MB
    f16* ba   = (f16*)(ws + o); o += (size_t)NK * 512 * 2;   // 32 MB
    f16* h1   = (f16*)(ws + o); o += (size_t)NK * DIM * 2;   // 16 MB
    f16* qf   = (f16*)(ws + o); o += (size_t)MQ * DIM * 2;
    f16* q1f  = (f16*)(ws + o); o += 65536 * 2;
    f16* q2f  = (f16*)(ws + o); o += 65536 * 2;
    f16* k1f  = (f16*)(ws + o); o += 196608 * 2;
    f16* k2t  = (f16*)(ws + o); o += 65536 * 2;
    f16* yq   = (f16*)(ws + o); o += (size_t)MQ * DIM * 2;
    float* cvec = (float*)(ws + o); o += MQ * 4;
    float* cmax = (float*)(ws + o); o += (size_t)NCHUNK * DIM * 4;
    float* pbef = (float*)(ws + o); o += (size_t)NCHUNK * DIM * 4;
    float* paft = (float*)(ws + o); o += (size_t)NCHUNK * DIM * 4;
    float* stot = (float*)(ws + o); o += 2 * NSEG * DIM * 4;
    float* spref = (float*)(ws + o); o += 2 * NSEG * DIM * 4;

    convert_kernel<<<2560, 256, 0, stream>>>(query, q1_w, q2_w, k1_w, k2_w,
                                             qf, q1f, q2f, k1f, k2t);
    chunkmax_kernel<<<NCHUNK, 128, 0, stream>>>(key, keyf, cmax);
    segscan_kernel<<<2 * NSEG, 256, 0, stream>>>(cmax, pbef, paft, stot);
    segpref_kernel<<<1, 256, 0, stream>>>(stot, spref);
    scanwrite_kernel<<<NCHUNK, 128, 0, stream>>>(keyf, pbef, paft, spref, ba);
    qmlp_kernel<<<MQ / 64, 256, 0, stream>>>(qf, q1f, q2f, k2t,
                                             q1_b, q2_b, k2_b, yq, cvec);

    // K4: h1 = relu([key_f16|befaft] @ k1_w^T + k1_b)   M=32768 N=256 K=768
    gemm_f16<768, 1, true, true, true><<<dim3(2, NK / 128), 256, 0, stream>>>(
        keyf, ba, k1f, k1_b, nullptr, nullptr, h1, DIM, 1.0f);
    // K5: out = yq @ h1^T / 16 + c[m]   M=1024 N=32768 K=256, BM=256 BN=128
    gemm_final<<<dim3(256, 4), 512, 0, stream>>>(yq, h1, cvec, out);
}

// Round 11
// 132.911 us; speedup vs baseline: 1.0543x; 1.0543x over previous
//
#include <hip/hip_runtime.h>
#include <hip/hip_bf16.h>

// CrossAttentionSequencePool — fp16 MFMA; r7 GEMM structure (proven optimum:
// r6 depth-4 ✗, r9 3-ring ✗, r10 reg-A ✗) + scan-path HBM traffic cuts.
//  convert: weights/query -> f16 (k2 transposed)
//  chunkmax: key -> per-chunk fp32 col max ONLY (keyf write moved out)
//  segscan: seg-level exclusive partials + totals
//  scanwrite: reads key fp32 (L3-resident after chunkmax), emits keyf f16 +
//             befaft f16; segment prefix inlined from stot (segpref deleted)
//  qmlp (16 blocks): unified 24-iter depth-2 pipeline, hq1->xq->yq,c
//  K4 gemm<768,2part,relu>: h1 = relu([keyf|ba] @ k1_w^T + k1_b)
//  K5 gemm<256>: out = yq @ h1^T /16 + c[m]  (nontemporal fp32 stream)
// GEMM: 128x128/BK=32, 4 waves, depth-2 counted-vmcnt, both-side atom-XOR
// swizzle (0 bank conflicts), XCD swizzle.

#define NK 32768
#define DIM 256
#define MQ 1024
#define CHUNK 32
#define NCHUNK (NK / CHUNK) // 1024
#define NSEG 32
#define SEGCH (NCHUNK / NSEG) // 32

typedef _Float16 f16;
typedef _Float16 f16x2 __attribute__((ext_vector_type(2)));
typedef _Float16 f16x8 __attribute__((ext_vector_type(8)));
typedef float f32x4 __attribute__((ext_vector_type(4)));

__device__ __forceinline__ void gload16(const void* g, void* l) {
    __builtin_amdgcn_global_load_lds(
        (const __attribute__((address_space(1))) unsigned int*)g,
        (__attribute__((address_space(3))) unsigned int*)l, 16, 0, 0);
}

// ---------------- chunkmax: per-chunk fp32 col max only ----------------
__global__ __launch_bounds__(128) void chunkmax_kernel(const float* __restrict__ key,
                                                       float* __restrict__ cmax) {
    int t = threadIdx.x, c = blockIdx.x;
    int c0 = t * 2;
    float m0 = -INFINITY, m1 = -INFINITY;
#pragma unroll 8
    for (int r = 0; r < CHUNK; ++r) {
        int gr = c * CHUNK + r;
        float2 kv = *reinterpret_cast<const float2*>(key + (size_t)gr * DIM + c0);
        m0 = fmaxf(m0, kv.x);
        m1 = fmaxf(m1, kv.y);
    }
    *reinterpret_cast<float2*>(cmax + c * DIM + c0) = make_float2(m0, m1);
}

// ---------------- segscan ----------------
__global__ __launch_bounds__(256) void segscan_kernel(const float* __restrict__ cmax,
                                                      float* __restrict__ pbef,
                                                      float* __restrict__ paft,
                                                      float* __restrict__ stot) {
    int col = threadIdx.x, b = blockIdx.x;
    int dir = b >> 5, s = b & 31;
    float run = -INFINITY;
    if (dir == 0) {
#pragma unroll 8
        for (int i = 0; i < SEGCH; ++i) {
            int c = s * SEGCH + i;
            pbef[c * DIM + col] = run;
            run = fmaxf(run, cmax[c * DIM + col]);
        }
        stot[s * DIM + col] = run;
    } else {
#pragma unroll 8
        for (int i = SEGCH - 1; i >= 0; --i) {
            int c = s * SEGCH + i;
            paft[c * DIM + col] = run;
            run = fmaxf(run, cmax[c * DIM + col]);
        }
        stot[(NSEG + s) * DIM + col] = run;
    }
}

// ---------------- scanwrite: key(L3) -> keyf + befaft; segpref inlined ----------------
// Chain numerics identical to r7: prefix seeds from fp32 cmax-chain, in-chunk
// updates with f16-rounded key values (monotone rnd).
__global__ __launch_bounds__(128) void scanwrite_kernel(const float* __restrict__ key,
                                                        const float* __restrict__ pbef,
                                                        const float* __restrict__ paft,
                                                        const float* __restrict__ stot,
                                                        f16* __restrict__ keyf,
                                                        f16* __restrict__ ba) {
    __shared__ f16 sk[CHUNK * DIM];
    int t = threadIdx.x, c = blockIdx.x, s = c >> 5;
    int c0 = t * 2;
    // segment prefix (fwd) from stot[0..s-1] — L2-hot, <=31 loads/col
    float s0 = -INFINITY, s1 = -INFINITY;
    for (int u = 0; u < s; ++u) {
        s0 = fmaxf(s0, stot[u * DIM + c0]);
        s1 = fmaxf(s1, stot[u * DIM + c0 + 1]);
    }
    float r0 = fmaxf(pbef[c * DIM + c0], s0);
    float r1 = fmaxf(pbef[c * DIM + c0 + 1], s1);
    for (int r = 0; r < CHUNK; ++r) {
        int gr = c * CHUNK + r;
        float2 kf = *reinterpret_cast<const float2*>(key + (size_t)gr * DIM + c0);
        f16x2 kv = (f16x2){(f16)kf.x, (f16)kf.y};
        *reinterpret_cast<f16x2*>(keyf + (size_t)gr * DIM + c0) = kv;
        *reinterpret_cast<f16x2*>(sk + r * DIM + c0) = kv;
        *reinterpret_cast<f16x2*>(ba + (size_t)gr * 512 + c0) =
            (f16x2){(f16)(gr == 0 ? 0.f : r0), (f16)(gr == 0 ? 0.f : r1)};
        r0 = fmaxf(r0, (float)kv.x);
        r1 = fmaxf(r1, (float)kv.y);
    }
    // segment suffix (bwd) from stot[NSEG+s+1 .. 2*NSEG-1]
    float a0 = -INFINITY, a1 = -INFINITY;
    for (int u = s + 1; u < NSEG; ++u) {
        a0 = fmaxf(a0, stot[(NSEG + u) * DIM + c0]);
        a1 = fmaxf(a1, stot[(NSEG + u) * DIM + c0 + 1]);
    }
    r0 = fmaxf(paft[c * DIM + c0], a0);
    r1 = fmaxf(paft[c * DIM + c0 + 1], a1);
    for (int r = CHUNK - 1; r >= 0; --r) {
        int gr = c * CHUNK + r;
        f16x2 kv = *reinterpret_cast<const f16x2*>(sk + r * DIM + c0);
        *reinterpret_cast<f16x2*>(ba + (size_t)gr * 512 + 256 + c0) =
            (f16x2){(f16)(gr == NK - 1 ? 0.f : r0), (f16)(gr == NK - 1 ? 0.f : r1)};
        r0 = fmaxf(r0, (float)kv.x);
        r1 = fmaxf(r1, (float)kv.y);
    }
}

// ---------------- convert (r7-verbatim) ----------------
__global__ __launch_bounds__(256) void convert_kernel(
    const float* __restrict__ q, const float* __restrict__ q1w, const float* __restrict__ q2w,
    const float* __restrict__ k1w, const float* __restrict__ k2w,
    f16* qf, f16* q1f, f16* q2f, f16* k1f, f16* k2t) {
    int i = blockIdx.x * 256 + threadIdx.x;
    if (i < 262144)      { qf[i] = (f16)q[i]; }
    else if (i < 327680) { int o = i - 262144; q1f[o] = (f16)q1w[o]; }
    else if (i < 393216) { int o = i - 327680; q2f[o] = (f16)q2w[o]; }
    else if (i < 589824) { int o = i - 393216; k1f[o] = (f16)k1w[o]; }
    else { // k2t[n][k] = k2[k][n]
        int o = i - 589824;
        int k = o >> 8, n = o & 255;
        k2t[n * 256 + k] = (f16)k2w[o];
    }
}

// ---------------- fused query MLP (r7-verbatim) ----------------
__global__ __launch_bounds__(256) void qmlp_kernel(
    const f16* __restrict__ qf, const f16* __restrict__ q1f,
    const f16* __restrict__ q2f, const f16* __restrict__ k2t,
    const float* __restrict__ q1_b, const float* __restrict__ q2_b,
    const float* __restrict__ k2_b,
    f16* __restrict__ yq, float* __restrict__ cvec) {
    __shared__ __align__(16) f16 hbuf[8 * 64 * 32];
    __shared__ __align__(16) f16 sB[2][256 * 32];
    __shared__ float cpart[64][4];
    const int t = threadIdx.x, lane = t & 63, wid = t >> 6;
    const int m0 = blockIdx.x * 64;
    const int l15 = lane & 15, l4 = lane >> 4, r16 = lane >> 2;
    const int cSw = ((lane & 3) ^ ((lane >> 3) & 3)) * 8;
    const int sw = (l4 ^ ((l15 >> 1) & 3)) * 8;

    auto hb_addr = [&](int row, int col) {
        return (col >> 5) * 2048 + row * 32 +
               ((((col & 31) >> 3) ^ ((row >> 1) & 3)) << 3) + (col & 7);
    };
    auto stageB = [&](int u, int b) {
        const f16* B = u < 8 ? q1f : (u < 16 ? q2f : k2t);
        const int tt = u & 7;
#pragma unroll
        for (int cc = 0; cc < 4; ++cc) {
            int row = wid * 64 + cc * 16 + r16;
            gload16(B + (size_t)row * 256 + tt * 32 + cSw,
                    (char*)&sB[b][0] + (wid * 4 + cc) * 1024);
        }
    };

    f32x4 acc[4][4];
#define ZACC                                                        \
    _Pragma("unroll") for (int i = 0; i < 4; ++i)                   \
        _Pragma("unroll") for (int j = 0; j < 4; ++j) {             \
            acc[i][j][0] = 0.f; acc[i][j][1] = 0.f;                 \
            acc[i][j][2] = 0.f; acc[i][j][3] = 0.f;                 \
        }

#pragma unroll
    for (int tt = 0; tt < 8; ++tt)
        gload16(qf + (size_t)(m0 + wid * 16 + r16) * 256 + tt * 32 + cSw,
                (char*)hbuf + tt * 4096 + wid * 1024);
    stageB(0, 0);
    stageB(1, 1);
    asm volatile("s_waitcnt vmcnt(4)" ::: "memory");
    __builtin_amdgcn_s_barrier();

    ZACC
    for (int u = 0; u < 24; ++u) {
        const int tt = u & 7, b = u & 1;
        f16x8 fa[4], fb[4];
#pragma unroll
        for (int i = 0; i < 4; ++i)
            fa[i] = *reinterpret_cast<const f16x8*>(&hbuf[tt * 2048 + (i * 16 + l15) * 32 + sw]);
#pragma unroll
        for (int j = 0; j < 4; ++j)
            fb[j] = *reinterpret_cast<const f16x8*>(&sB[b][(wid * 64 + j * 16 + l15) * 32 + sw]);
        asm volatile("s_waitcnt lgkmcnt(0)" ::: "memory");
        __builtin_amdgcn_s_barrier();
        if (u + 2 < 24) stageB(u + 2, b);
        __builtin_amdgcn_s_setprio(1);
#pragma unroll
        for (int i = 0; i < 4; ++i)
#pragma unroll
            for (int j = 0; j < 4; ++j)
                acc[i][j] = __builtin_amdgcn_mfma_f32_16x16x32_f16(fa[i], fb[j], acc[i][j], 0, 0, 0);
        __builtin_amdgcn_s_setprio(0);
        if (u == 7) {
#pragma unroll
            for (int j = 0; j < 4; ++j) {
                int col = wid * 64 + j * 16 + l15;
                float bv = q1_b[col];
#pragma unroll
                for (int i = 0; i < 4; ++i)
#pragma unroll
                    for (int r = 0; r < 4; ++r)
                        hbuf[hb_addr(i * 16 + l4 * 4 + r, col)] =
                            (f16)fmaxf(acc[i][j][r] + bv, 0.f);
            }
            asm volatile("s_waitcnt lgkmcnt(0)" ::: "memory");
            ZACC
        }
        if (u == 15) {
#pragma unroll
            for (int j = 0; j < 4; ++j) {
                int col = wid * 64 + j * 16 + l15;
                float bv = q2_b[col];
#pragma unroll
                for (int i = 0; i < 4; ++i)
#pragma unroll
                    for (int r = 0; r < 4; ++r)
                        hbuf[hb_addr(i * 16 + l4 * 4 + r, col)] = (f16)(acc[i][j][r] + bv);
            }
            asm volatile("s_waitcnt lgkmcnt(0)" ::: "memory");
            ZACC
        }
        if (u + 2 < 24) {
            asm volatile("s_waitcnt vmcnt(4)" ::: "memory");
        } else {
            asm volatile("s_waitcnt vmcnt(0)" ::: "memory");
        }
        __builtin_amdgcn_s_barrier();
    }
#undef ZACC

#pragma unroll
    for (int j = 0; j < 4; ++j) {
        int col = wid * 64 + j * 16 + l15;
#pragma unroll
        for (int i = 0; i < 4; ++i)
#pragma unroll
            for (int r = 0; r < 4; ++r)
                yq[(size_t)(m0 + i * 16 + l4 * 4 + r) * 256 + col] = (f16)acc[i][j][r];
    }
    {
        int row = t & 63, qtr = t >> 6;
        float s = 0.f;
        for (int k = qtr * 64; k < qtr * 64 + 64; ++k)
            s += (float)hbuf[hb_addr(row, k)] * k2_b[k];
        cpart[row][qtr] = s;
    }
    __syncthreads();
    if (t < 64)
        cvec[m0 + t] = (cpart[t][0] + cpart[t][1] + cpart[t][2] + cpart[t][3]) * 0.0625f;
}

// ---------------- fp16 MFMA GEMM (NT), depth-2 pipeline (r7-verbatim) ----------------
// TWOPART: A = [A0 ld256 (tt<8) | A1 ld512 (tt>=8)] for K=768.
template <int K, int SWZ, bool TWOPART, bool RELU, bool OUTF16>
__global__ __launch_bounds__(256, 4) void gemm_f16(
    const f16* __restrict__ A0, const f16* __restrict__ A1,
    const f16* __restrict__ B,
    const float* __restrict__ bias, const float* __restrict__ rowbias,
    float* __restrict__ Cf, f16* __restrict__ Ch,
    int N, float scale) {
    __shared__ __align__(16) f16 sA[2][128 * 32];
    __shared__ __align__(16) f16 sB[2][128 * 32];
    const int t = threadIdx.x;
    const int lane = t & 63, wid = t >> 6;

    int mt, nt;
    if (SWZ == 1) {
        int bid = blockIdx.y * gridDim.x + blockIdx.x;
        int xcd = bid & 7, i = bid >> 3;
        mt = xcd * 32 + (i >> 1);
        nt = i & 1;
    } else if (SWZ == 2) {
        int bid = blockIdx.y * gridDim.x + blockIdx.x;
        int xcd = bid & 7, i = bid >> 3;
        nt = xcd * 32 + (i & 31);
        mt = i >> 5;
    } else {
        mt = blockIdx.y;
        nt = blockIdx.x;
    }
    const int m0 = mt * 128, n0 = nt * 128;
    const int wr = wid >> 1, wc = wid & 1;
    const int l15 = lane & 15, l4 = lane >> 4;
    constexpr int T = K / 32;

    const int row0 = wid * 16 + (lane >> 2);
    const int row1 = row0 + 64;
    const int cSw = ((lane & 3) ^ ((lane >> 3) & 3)) * 8;
    const unsigned off0 = (unsigned)(wid * 1024);
    const unsigned off1 = off0 + 4096;

    f32x4 acc[4][4];
#pragma unroll
    for (int i = 0; i < 4; ++i)
#pragma unroll
        for (int j = 0; j < 4; ++j) {
            acc[i][j][0] = 0.f; acc[i][j][1] = 0.f; acc[i][j][2] = 0.f; acc[i][j][3] = 0.f;
        }

    auto aadr = [&](int row, int tt) -> const f16* {
        if (TWOPART && tt >= 8) return A1 + (size_t)row * 512 + (tt - 8) * 32 + cSw;
        return A0 + (size_t)row * (TWOPART ? 256 : K) + tt * 32 + cSw;
    };
    auto stage = [&](int tt, int bb) {
        gload16(aadr(m0 + row0, tt), (char*)&sA[bb][0] + off0);
        gload16(aadr(m0 + row1, tt), (char*)&sA[bb][0] + off1);
        gload16(B + (size_t)(n0 + row0) * K + tt * 32 + cSw, (char*)&sB[bb][0] + off0);
        gload16(B + (size_t)(n0 + row1) * K + tt * 32 + cSw, (char*)&sB[bb][0] + off1);
    };

    stage(0, 0);
    stage(1, 1);
    asm volatile("s_waitcnt vmcnt(4)" ::: "memory");
    __builtin_amdgcn_s_barrier();

    for (int tt = 0; tt < T; ++tt) {
        const int b = tt & 1;
        f16x8 fa[4], fb[4];
#pragma unroll
        for (int i = 0; i < 4; ++i) {
            const int sw = (l4 ^ ((l15 >> 1) & 3)) * 8;
            fa[i] = *reinterpret_cast<const f16x8*>(&sA[b][(wr * 64 + i * 16 + l15) * 32 + sw]);
            fb[i] = *reinterpret_cast<const f16x8*>(&sB[b][(wc * 64 + i * 16 + l15) * 32 + sw]);
        }
        asm volatile("s_waitcnt lgkmcnt(0)" ::: "memory");
        __builtin_amdgcn_s_barrier();
        if (tt + 2 < T) stage(tt + 2, b);
        __builtin_amdgcn_s_setprio(1);
#pragma unroll
        for (int i = 0; i < 4; ++i)
#pragma unroll
            for (int j = 0; j < 4; ++j)
                acc[i][j] = __builtin_amdgcn_mfma_f32_16x16x32_f16(fa[i], fb[j], acc[i][j], 0, 0, 0);
        __builtin_amdgcn_s_setprio(0);
        if (tt + 2 < T) {
            asm volatile("s_waitcnt vmcnt(4)" ::: "memory");
        } else {
            asm volatile("s_waitcnt vmcnt(0)" ::: "memory");
        }
        __builtin_amdgcn_s_barrier();
    }

    // epilogue: C row = 4*(lane>>4)+reg, col = lane&15
#pragma unroll
    for (int j = 0; j < 4; ++j) {
        int col = n0 + wc * 64 + j * 16 + l15;
        float bv = bias ? bias[col] : 0.0f;
#pragma unroll
        for (int i = 0; i < 4; ++i) {
            int rbase = m0 + wr * 64 + i * 16 + l4 * 4;
#pragma unroll
            for (int r = 0; r < 4; ++r) {
                float v = acc[i][j][r] + bv;
                if (RELU) v = fmaxf(v, 0.0f);
                v *= scale;
                if (rowbias) v += rowbias[rbase + r];
                size_t idx = (size_t)(rbase + r) * N + col;
                if (OUTF16) {
                    Ch[idx] = (f16)v;
                } else {
                    __builtin_nontemporal_store(v, Cf + idx); // 134MB stream, never re-read
                }
            }
        }
    }
}

extern "C" void kernel_launch(void* const* d_in, const int* in_sizes, int n_in,
                              void* d_out, int out_size, void* d_ws, size_t ws_size,
                              hipStream_t stream) {
    const float* query = (const float*)d_in[0];
    const float* key   = (const float*)d_in[1];
    const float* q1_w  = (const float*)d_in[2];
    const float* q1_b  = (const float*)d_in[3];
    const float* q2_w  = (const float*)d_in[4];
    const float* q2_b  = (const float*)d_in[5];
    const float* k1_w  = (const float*)d_in[6];
    const float* k1_b  = (const float*)d_in[7];
    const float* k2_w  = (const float*)d_in[8];
    const float* k2_b  = (const float*)d_in[9];
    float* out = (float*)d_out;

    char* ws = (char*)d_ws;
    size_t o = 0;
    f16* keyf = (f16*)(ws + o); o += (size_t)NK * DIM * 2;   // 16 MB
    f16* ba   = (f16*)(ws + o); o += (size_t)NK * 512 * 2;   // 32 MB
    f16* h1   = (f16*)(ws + o); o += (size_t)NK * DIM * 2;   // 16 MB
    f16* qf   = (f16*)(ws + o); o += (size_t)MQ * DIM * 2;
    f16* q1f  = (f16*)(ws + o); o += 65536 * 2;
    f16* q2f  = (f16*)(ws + o); o += 65536 * 2;
    f16* k1f  = (f16*)(ws + o); o += 196608 * 2;
    f16* k2t  = (f16*)(ws + o); o += 65536 * 2;
    f16* yq   = (f16*)(ws + o); o += (size_t)MQ * DIM * 2;
    float* cvec = (float*)(ws + o); o += MQ * 4;
    float* cmax = (float*)(ws + o); o += (size_t)NCHUNK * DIM * 4;
    float* pbef = (float*)(ws + o); o += (size_t)NCHUNK * DIM * 4;
    float* paft = (float*)(ws + o); o += (size_t)NCHUNK * DIM * 4;
    float* stot = (float*)(ws + o); o += 2 * NSEG * DIM * 4;

    convert_kernel<<<2560, 256, 0, stream>>>(query, q1_w, q2_w, k1_w, k2_w,
                                             qf, q1f, q2f, k1f, k2t);
    chunkmax_kernel<<<NCHUNK, 128, 0, stream>>>(key, cmax);
    segscan_kernel<<<2 * NSEG, 256, 0, stream>>>(cmax, pbef, paft, stot);
    scanwrite_kernel<<<NCHUNK, 128, 0, stream>>>(key, pbef, paft, stot, keyf, ba);
    qmlp_kernel<<<MQ / 64, 256, 0, stream>>>(qf, q1f, q2f, k2t,
                                             q1_b, q2_b, k2_b, yq, cvec);

    // K4: h1 = relu([keyf|ba] @ k1_w^T + k1_b)   M=32768 N=256 K=768
    gemm_f16<768, 1, true, true, true><<<dim3(2, NK / 128), 256, 0, stream>>>(
        keyf, ba, k1f, k1_b, nullptr, nullptr, h1, DIM, 1.0f);
    // K5: out = yq @ h1^T / 16 + c[m]            M=1024 N=32768 K=256
    gemm_f16<256, 2, false, false, false><<<dim3(NK / 128, MQ / 128), 256, 0, stream>>>(
        yq, nullptr, h1, nullptr, cvec, out, nullptr, NK, 0.0625f);
}

// Round 12
// 125.615 us; speedup vs baseline: 1.1155x; 1.0581x over previous
//
#include <hip/hip_runtime.h>
#include <hip/hip_bf16.h>

// CrossAttentionSequencePool — fp16 MFMA; r5-proven depth-2 GEMM + key-split
// scan + fully-pipelined qmlp.  [EXACT revert to the round-7 kernel, the
// measured best (125.8 µs). Structural variants all regressed:
//  r6 depth-4 ring ✗ (occupancy), r8 launch-fusion ±0, r9 3-ring ✗,
//  r10 reg-A final GEMM ✗ (latency-bound), r11 L3-re-read scan ✗.]
//  out = yq @ h1^T /16 + c[m]   (x_key GEMM algebraically eliminated, r5)
//  chunkmax: key -> key_f16 + per-chunk fp32 col max (CHUNK=32)
//  segscan/segpref/scanwrite: 3-level exclusive prefix/suffix max -> befaft f16
//  gemm<768,2part,relu>: h1 = relu([key_f16|befaft] @ k1_w^T + k1_b)
//  qmlp (16 blocks): unified 24-iter depth-2 pipeline over q1f/q2f/k2t panels,
//                    A always read from hbuf (qf -> h -> xq in place)
//  final gemm<256>: out = yq @ h1^T * 1/16 + c
// GEMM: 128x128/BK=32, 4 waves, depth-2 (32KB LDS, 4 blocks/CU). Both-side
// atom-XOR swizzle (r3: 0 bank conflicts). XCD swizzle (T1).

#define NK 32768
#define DIM 256
#define MQ 1024
#define CHUNK 32
#define NCHUNK (NK / CHUNK) // 1024
#define NSEG 32
#define SEGCH (NCHUNK / NSEG) // 32

typedef _Float16 f16;
typedef _Float16 f16x2 __attribute__((ext_vector_type(2)));
typedef _Float16 f16x8 __attribute__((ext_vector_type(8)));
typedef float f32x4 __attribute__((ext_vector_type(4)));

__device__ __forceinline__ void gload16(const void* g, void* l) {
    __builtin_amdgcn_global_load_lds(
        (const __attribute__((address_space(1))) unsigned int*)g,
        (__attribute__((address_space(3))) unsigned int*)l, 16, 0, 0);
}

// ---------------- scan ----------------
// key fp32 -> key_f16 (rnd monotone: f16-domain scan == rnd of fp32 scan) + chunk max
__global__ __launch_bounds__(128) void chunkmax_kernel(const float* __restrict__ key,
                                                       f16* __restrict__ keyf,
                                                       float* __restrict__ cmax) {
    int t = threadIdx.x, c = blockIdx.x;
    int c0 = t * 2;
    float m0 = -INFINITY, m1 = -INFINITY;
#pragma unroll 8
    for (int r = 0; r < CHUNK; ++r) {
        int gr = c * CHUNK + r;
        float2 kv = *reinterpret_cast<const float2*>(key + (size_t)gr * DIM + c0);
        *reinterpret_cast<f16x2*>(keyf + (size_t)gr * DIM + c0) = (f16x2){(f16)kv.x, (f16)kv.y};
        m0 = fmaxf(m0, kv.x);
        m1 = fmaxf(m1, kv.y);
    }
    *reinterpret_cast<float2*>(cmax + c * DIM + c0) = make_float2(m0, m1);
}

// 64 blocks: 0..31 forward segs, 32..63 backward. Exclusive partials + seg totals.
__global__ __launch_bounds__(256) void segscan_kernel(const float* __restrict__ cmax,
                                                      float* __restrict__ pbef,
                                                      float* __restrict__ paft,
                                                      float* __restrict__ stot) {
    int col = threadIdx.x, b = blockIdx.x;
    int dir = b >> 5, s = b & 31;
    float run = -INFINITY;
    if (dir == 0) {
#pragma unroll 8
        for (int i = 0; i < SEGCH; ++i) {
            int c = s * SEGCH + i;
            pbef[c * DIM + col] = run;
            run = fmaxf(run, cmax[c * DIM + col]);
        }
        stot[s * DIM + col] = run;
    } else {
#pragma unroll 8
        for (int i = SEGCH - 1; i >= 0; --i) {
            int c = s * SEGCH + i;
            paft[c * DIM + col] = run;
            run = fmaxf(run, cmax[c * DIM + col]);
        }
        stot[(NSEG + s) * DIM + col] = run;
    }
}

__global__ __launch_bounds__(256) void segpref_kernel(const float* __restrict__ stot,
                                                      float* __restrict__ spref) {
    int col = threadIdx.x;
    float run = -INFINITY;
#pragma unroll
    for (int s = 0; s < NSEG; ++s) {
        spref[s * DIM + col] = run;
        run = fmaxf(run, stot[s * DIM + col]);
    }
    run = -INFINITY;
#pragma unroll
    for (int s = NSEG - 1; s >= 0; --s) {
        spref[(NSEG + s) * DIM + col] = run;
        run = fmaxf(run, stot[(NSEG + s) * DIM + col]);
    }
}

// befaft[r] = [x_before | x_after] f16, ld 512. Reads key_f16 (monotone-rnd safe).
__global__ __launch_bounds__(128) void scanwrite_kernel(const f16* __restrict__ keyf,
                                                        const float* __restrict__ pbef,
                                                        const float* __restrict__ paft,
                                                        const float* __restrict__ spref,
                                                        f16* __restrict__ ba) {
    __shared__ f16 sk[CHUNK * DIM];
    int t = threadIdx.x, c = blockIdx.x, s = c >> 5;
    int c0 = t * 2;
    float r0 = fmaxf(pbef[c * DIM + c0], spref[s * DIM + c0]);
    float r1 = fmaxf(pbef[c * DIM + c0 + 1], spref[s * DIM + c0 + 1]);
    for (int r = 0; r < CHUNK; ++r) {
        int gr = c * CHUNK + r;
        f16x2 kv = *reinterpret_cast<const f16x2*>(keyf + (size_t)gr * DIM + c0);
        *reinterpret_cast<f16x2*>(sk + r * DIM + c0) = kv;
        *reinterpret_cast<f16x2*>(ba + (size_t)gr * 512 + c0) =
            (f16x2){(f16)(gr == 0 ? 0.f : r0), (f16)(gr == 0 ? 0.f : r1)};
        r0 = fmaxf(r0, (float)kv.x);
        r1 = fmaxf(r1, (float)kv.y);
    }
    r0 = fmaxf(paft[c * DIM + c0], spref[(NSEG + s) * DIM + c0]);
    r1 = fmaxf(paft[c * DIM + c0 + 1], spref[(NSEG + s) * DIM + c0 + 1]);
    for (int r = CHUNK - 1; r >= 0; --r) {
        int gr = c * CHUNK + r;
        f16x2 kv = *reinterpret_cast<const f16x2*>(sk + r * DIM + c0);
        *reinterpret_cast<f16x2*>(ba + (size_t)gr * 512 + 256 + c0) =
            (f16x2){(f16)(gr == NK - 1 ? 0.f : r0), (f16)(gr == NK - 1 ? 0.f : r1)};
        r0 = fmaxf(r0, (float)kv.x);
        r1 = fmaxf(r1, (float)kv.y);
    }
}

// ---------------- convert: query + weights to f16 (k2 transposed) ----------------
__global__ __launch_bounds__(256) void convert_kernel(
    const float* __restrict__ q, const float* __restrict__ q1w, const float* __restrict__ q2w,
    const float* __restrict__ k1w, const float* __restrict__ k2w,
    f16* qf, f16* q1f, f16* q2f, f16* k1f, f16* k2t) {
    int i = blockIdx.x * 256 + threadIdx.x;
    if (i < 262144)      { qf[i] = (f16)q[i]; }
    else if (i < 327680) { int o = i - 262144; q1f[o] = (f16)q1w[o]; }
    else if (i < 393216) { int o = i - 327680; q2f[o] = (f16)q2w[o]; }
    else if (i < 589824) { int o = i - 393216; k1f[o] = (f16)k1w[o]; }
    else { // k2t[n][k] = k2[k][n]
        int o = i - 589824;
        int k = o >> 8, n = o & 255;
        k2t[n * 256 + k] = (f16)k2w[o];
    }
}

// ---------------- fused query MLP, unified depth-2 pipeline ----------------
// 16 blocks x 4 waves, 64-row tile. A lives in hbuf throughout:
//   iters 0-7:  A = qf (preloaded), B = q1f  -> h written back to hbuf
//   iters 8-15: A = h,              B = q2f  -> xq written back to hbuf
//   iters 16-23:A = xq,             B = k2t  -> yq to global; cvec from hbuf
__global__ __launch_bounds__(256) void qmlp_kernel(
    const f16* __restrict__ qf, const f16* __restrict__ q1f,
    const f16* __restrict__ q2f, const f16* __restrict__ k2t,
    const float* __restrict__ q1_b, const float* __restrict__ q2_b,
    const float* __restrict__ k2_b,
    f16* __restrict__ yq, float* __restrict__ cvec) {
    __shared__ __align__(16) f16 hbuf[8 * 64 * 32]; // 32KB: 8 panels [64r][32k]
    __shared__ __align__(16) f16 sB[2][256 * 32];   // 32KB double-buffered
    __shared__ float cpart[64][4];
    const int t = threadIdx.x, lane = t & 63, wid = t >> 6;
    const int m0 = blockIdx.x * 64;
    const int l15 = lane & 15, l4 = lane >> 4, r16 = lane >> 2;
    const int cSw = ((lane & 3) ^ ((lane >> 3) & 3)) * 8;
    const int sw = (l4 ^ ((l15 >> 1) & 3)) * 8;

    auto hb_addr = [&](int row, int col) {
        return (col >> 5) * 2048 + row * 32 +
               ((((col & 31) >> 3) ^ ((row >> 1) & 3)) << 3) + (col & 7);
    };
    auto stageB = [&](int u, int b) { // 4 loads/wave
        const f16* B = u < 8 ? q1f : (u < 16 ? q2f : k2t);
        const int tt = u & 7;
#pragma unroll
        for (int cc = 0; cc < 4; ++cc) {
            int row = wid * 64 + cc * 16 + r16;
            gload16(B + (size_t)row * 256 + tt * 32 + cSw,
                    (char*)&sB[b][0] + (wid * 4 + cc) * 1024);
        }
    };

    f32x4 acc[4][4];
#define ZACC                                                        \
    _Pragma("unroll") for (int i = 0; i < 4; ++i)                   \
        _Pragma("unroll") for (int j = 0; j < 4; ++j) {             \
            acc[i][j][0] = 0.f; acc[i][j][1] = 0.f;                 \
            acc[i][j][2] = 0.f; acc[i][j][3] = 0.f;                 \
        }

    // prologue: hbuf <- qf tile (8 panels, 8 loads/wave) + stage u=0,1
#pragma unroll
    for (int tt = 0; tt < 8; ++tt)
        gload16(qf + (size_t)(m0 + wid * 16 + r16) * 256 + tt * 32 + cSw,
                (char*)hbuf + tt * 4096 + wid * 1024);
    stageB(0, 0);
    stageB(1, 1);
    asm volatile("s_waitcnt vmcnt(4)" ::: "memory"); // hbuf + tile0 done, tile1 in flight
    __builtin_amdgcn_s_barrier();

    ZACC
    for (int u = 0; u < 24; ++u) {
        const int tt = u & 7, b = u & 1;
        f16x8 fa[4], fb[4];
#pragma unroll
        for (int i = 0; i < 4; ++i)
            fa[i] = *reinterpret_cast<const f16x8*>(&hbuf[tt * 2048 + (i * 16 + l15) * 32 + sw]);
#pragma unroll
        for (int j = 0; j < 4; ++j)
            fb[j] = *reinterpret_cast<const f16x8*>(&sB[b][(wid * 64 + j * 16 + l15) * 32 + sw]);
        asm volatile("s_waitcnt lgkmcnt(0)" ::: "memory");
        __builtin_amdgcn_s_barrier();      // all waves done reading sB[b] / hbuf[tt]
        if (u + 2 < 24) stageB(u + 2, b);  // overwrite sB[b]
        __builtin_amdgcn_s_setprio(1);
#pragma unroll
        for (int i = 0; i < 4; ++i)
#pragma unroll
            for (int j = 0; j < 4; ++j)
                acc[i][j] = __builtin_amdgcn_mfma_f32_16x16x32_f16(fa[i], fb[j], acc[i][j], 0, 0, 0);
        __builtin_amdgcn_s_setprio(0);
        if (u == 7) { // h = relu(acc + q1_b) -> hbuf (published by end barrier)
#pragma unroll
            for (int j = 0; j < 4; ++j) {
                int col = wid * 64 + j * 16 + l15;
                float bv = q1_b[col];
#pragma unroll
                for (int i = 0; i < 4; ++i)
#pragma unroll
                    for (int r = 0; r < 4; ++r)
                        hbuf[hb_addr(i * 16 + l4 * 4 + r, col)] =
                            (f16)fmaxf(acc[i][j][r] + bv, 0.f);
            }
            asm volatile("s_waitcnt lgkmcnt(0)" ::: "memory");
            ZACC
        }
        if (u == 15) { // xq = acc + q2_b -> hbuf
#pragma unroll
            for (int j = 0; j < 4; ++j) {
                int col = wid * 64 + j * 16 + l15;
                float bv = q2_b[col];
#pragma unroll
                for (int i = 0; i < 4; ++i)
#pragma unroll
                    for (int r = 0; r < 4; ++r)
                        hbuf[hb_addr(i * 16 + l4 * 4 + r, col)] = (f16)(acc[i][j][r] + bv);
            }
            asm volatile("s_waitcnt lgkmcnt(0)" ::: "memory");
            ZACC
        }
        if (u + 2 < 24) {
            asm volatile("s_waitcnt vmcnt(4)" ::: "memory");
        } else {
            asm volatile("s_waitcnt vmcnt(0)" ::: "memory");
        }
        __builtin_amdgcn_s_barrier();
    }
#undef ZACC

    // yq = acc (phase 3 result) -> global
#pragma unroll
    for (int j = 0; j < 4; ++j) {
        int col = wid * 64 + j * 16 + l15;
#pragma unroll
        for (int i = 0; i < 4; ++i)
#pragma unroll
            for (int r = 0; r < 4; ++r)
                yq[(size_t)(m0 + i * 16 + l4 * 4 + r) * 256 + col] = (f16)acc[i][j][r];
    }
    // cvec from hbuf (still holds xq)
    {
        int row = t & 63, qtr = t >> 6;
        float s = 0.f;
        for (int k = qtr * 64; k < qtr * 64 + 64; ++k)
            s += (float)hbuf[hb_addr(row, k)] * k2_b[k];
        cpart[row][qtr] = s;
    }
    __syncthreads();
    if (t < 64)
        cvec[m0 + t] = (cpart[t][0] + cpart[t][1] + cpart[t][2] + cpart[t][3]) * 0.0625f;
}

// ---------------- fp16 MFMA GEMM (NT), depth-2 pipeline (r5-proven) ----------------
// TWOPART: A = [A0 ld256 (tt<8) | A1 ld512 (tt>=8)] for K=768.
template <int K, int SWZ, bool TWOPART, bool RELU, bool OUTF16>
__global__ __launch_bounds__(256, 4) void gemm_f16(
    const f16* __restrict__ A0, const f16* __restrict__ A1,
    const f16* __restrict__ B,
    const float* __restrict__ bias, const float* __restrict__ rowbias,
    float* __restrict__ Cf, f16* __restrict__ Ch,
    int N, float scale) {
    __shared__ __align__(16) f16 sA[2][128 * 32];
    __shared__ __align__(16) f16 sB[2][128 * 32];
    const int t = threadIdx.x;
    const int lane = t & 63, wid = t >> 6;

    int mt, nt;
    if (SWZ == 1) {
        int bid = blockIdx.y * gridDim.x + blockIdx.x;
        int xcd = bid & 7, i = bid >> 3;
        mt = xcd * 32 + (i >> 1);
        nt = i & 1;
    } else if (SWZ == 2) {
        int bid = blockIdx.y * gridDim.x + blockIdx.x;
        int xcd = bid & 7, i = bid >> 3;
        nt = xcd * 32 + (i & 31);
        mt = i >> 5;
    } else {
        mt = blockIdx.y;
        nt = blockIdx.x;
    }
    const int m0 = mt * 128, n0 = nt * 128;
    const int wr = wid >> 1, wc = wid & 1;
    const int l15 = lane & 15, l4 = lane >> 4;
    constexpr int T = K / 32;

    const int row0 = wid * 16 + (lane >> 2);
    const int row1 = row0 + 64;
    const int cSw = ((lane & 3) ^ ((lane >> 3) & 3)) * 8;
    const unsigned off0 = (unsigned)(wid * 1024);
    const unsigned off1 = off0 + 4096;

    f32x4 acc[4][4];
#pragma unroll
    for (int i = 0; i < 4; ++i)
#pragma unroll
        for (int j = 0; j < 4; ++j) {
            acc[i][j][0] = 0.f; acc[i][j][1] = 0.f; acc[i][j][2] = 0.f; acc[i][j][3] = 0.f;
        }

    auto aadr = [&](int row, int tt) -> const f16* {
        if (TWOPART && tt >= 8) return A1 + (size_t)row * 512 + (tt - 8) * 32 + cSw;
        return A0 + (size_t)row * (TWOPART ? 256 : K) + tt * 32 + cSw;
    };
    auto stage = [&](int tt, int bb) { // 4 loads/wave
        gload16(aadr(m0 + row0, tt), (char*)&sA[bb][0] + off0);
        gload16(aadr(m0 + row1, tt), (char*)&sA[bb][0] + off1);
        gload16(B + (size_t)(n0 + row0) * K + tt * 32 + cSw, (char*)&sB[bb][0] + off0);
        gload16(B + (size_t)(n0 + row1) * K + tt * 32 + cSw, (char*)&sB[bb][0] + off1);
    };

    stage(0, 0);
    stage(1, 1);
    asm volatile("s_waitcnt vmcnt(4)" ::: "memory");
    __builtin_amdgcn_s_barrier();

    for (int tt = 0; tt < T; ++tt) {
        const int b = tt & 1;
        f16x8 fa[4], fb[4];
#pragma unroll
        for (int i = 0; i < 4; ++i) {
            const int sw = (l4 ^ ((l15 >> 1) & 3)) * 8;
            fa[i] = *reinterpret_cast<const f16x8*>(&sA[b][(wr * 64 + i * 16 + l15) * 32 + sw]);
            fb[i] = *reinterpret_cast<const f16x8*>(&sB[b][(wc * 64 + i * 16 + l15) * 32 + sw]);
        }
        asm volatile("s_waitcnt lgkmcnt(0)" ::: "memory");
        __builtin_amdgcn_s_barrier();
        if (tt + 2 < T) stage(tt + 2, b);
        __builtin_amdgcn_s_setprio(1);
#pragma unroll
        for (int i = 0; i < 4; ++i)
#pragma unroll
            for (int j = 0; j < 4; ++j)
                acc[i][j] = __builtin_amdgcn_mfma_f32_16x16x32_f16(fa[i], fb[j], acc[i][j], 0, 0, 0);
        __builtin_amdgcn_s_setprio(0);
        if (tt + 2 < T) {
            asm volatile("s_waitcnt vmcnt(4)" ::: "memory");
        } else {
            asm volatile("s_waitcnt vmcnt(0)" ::: "memory");
        }
        __builtin_amdgcn_s_barrier();
    }

    // epilogue: C row = 4*(lane>>4)+reg, col = lane&15
#pragma unroll
    for (int j = 0; j < 4; ++j) {
        int col = n0 + wc * 64 + j * 16 + l15;
        float bv = bias ? bias[col] : 0.0f;
#pragma unroll
        for (int i = 0; i < 4; ++i) {
            int rbase = m0 + wr * 64 + i * 16 + l4 * 4;
#pragma unroll
            for (int r = 0; r < 4; ++r) {
                float v = acc[i][j][r] + bv;
                if (RELU) v = fmaxf(v, 0.0f);
                v *= scale;
                if (rowbias) v += rowbias[rbase + r];
                size_t idx = (size_t)(rbase + r) * N + col;
                if (OUTF16) Ch[idx] = (f16)v;
                else Cf[idx] = v;
            }
        }
    }
}

extern "C" void kernel_launch(void* const* d_in, const int* in_sizes, int n_in,
                              void* d_out, int out_size, void* d_ws, size_t ws_size,
                              hipStream_t stream) {
    const float* query = (const float*)d_in[0];
    const float* key   = (const float*)d_in[1];
    const float* q1_w  = (const float*)d_in[2];
    const float* q1_b  = (const float*)d_in[3];
    const float* q2_w  = (const float*)d_in[4];
    const float* q2_b  = (const float*)d_in[5];
    const float* k1_w  = (const float*)d_in[6];
    const float* k1_b  = (const float*)d_in[7];
    const float* k2_w  = (const float*)d_in[8];
    const float* k2_b  = (const float*)d_in[9];
    float* out = (float*)d_out;

    char* ws = (char*)d_ws;
    size_t o = 0;
    f16* keyf = (f16*)(ws + o); o += (size_t)NK * DIM * 2;   // 16 MB
    f16* ba   = (f16*)(ws + o); o += (size_t)NK * 512 * 2;   // 32 MB
    f16* h1   = (f16*)(ws + o); o += (size_t)NK * DIM * 2;   // 16 MB
    f16* qf   = (f16*)(ws + o); o += (size_t)MQ * DIM * 2;
    f16* q1f  = (f16*)(ws + o); o += 65536 * 2;
    f16* q2f  = (f16*)(ws + o); o += 65536 * 2;
    f16* k1f  = (f16*)(ws + o); o += 196608 * 2;
    f16* k2t  = (f16*)(ws + o); o += 65536 * 2;
    f16* yq   = (f16*)(ws + o); o += (size_t)MQ * DIM * 2;
    float* cvec = (float*)(ws + o); o += MQ * 4;
    float* cmax = (float*)(ws + o); o += (size_t)NCHUNK * DIM * 4;
    float* pbef = (float*)(ws + o); o += (size_t)NCHUNK * DIM * 4;
    float* paft = (float*)(ws + o); o += (size_t)NCHUNK * DIM * 4;
    float* stot = (float*)(ws + o); o += 2 * NSEG * DIM * 4;
    float* spref = (float*)(ws + o); o += 2 * NSEG * DIM * 4;

    convert_kernel<<<2560, 256, 0, stream>>>(query, q1_w, q2_w, k1_w, k2_w,
                                             qf, q1f, q2f, k1f, k2t);
    chunkmax_kernel<<<NCHUNK, 128, 0, stream>>>(key, keyf, cmax);
    segscan_kernel<<<2 * NSEG, 256, 0, stream>>>(cmax, pbef, paft, stot);
    segpref_kernel<<<1, 256, 0, stream>>>(stot, spref);
    scanwrite_kernel<<<NCHUNK, 128, 0, stream>>>(keyf, pbef, paft, spref, ba);
    qmlp_kernel<<<MQ / 64, 256, 0, stream>>>(qf, q1f, q2f, k2t,
                                             q1_b, q2_b, k2_b, yq, cvec);

    // h1 = relu([key_f16|befaft] @ k1_w^T + k1_b)   M=32768 N=256 K=768
    gemm_f16<768, 1, true, true, true><<<dim3(2, NK / 128), 256, 0, stream>>>(
        keyf, ba, k1f, k1_b, nullptr, nullptr, h1, DIM, 1.0f);
    // out = yq @ h1^T / 16 + c[m]                   M=1024 N=32768 K=256
    gemm_f16<256, 2, false, false, false><<<dim3(NK / 128, MQ / 128), 256, 0, stream>>>(
        yq, nullptr, h1, nullptr, cvec, out, nullptr, NK, 0.0625f);
}